// Round 6
// baseline (612.973 us; speedup 1.0000x reference)
//
#include <hip/hip_runtime.h>

#define MM 2048   // memory slots
#define BB 64     // batch
#define TT 4      // tokens per slot
#define DD 128    // embed dim
#define VV 50000  // vocab
#define VPAD 50176  // VV rounded up to multiple of 256
#define NBLK_O 784  // gemm_o partial blocks (64 v-rows each)

__device__ __forceinline__ float dot4(const float4 a, const float4 b) {
    return __builtin_fmaf(a.x, b.x, __builtin_fmaf(a.y, b.y,
           __builtin_fmaf(a.z, b.z, a.w * b.w)));
}

// ---- zero u ----
__global__ void k_zero(float* __restrict__ u) {
    u[blockIdx.x * 256 + threadIdx.x] = 0.f;
}

// ---- zero W (float4 per thread) ----
__global__ void k_zero_w(float4* __restrict__ w) {
    w[blockIdx.x * 256 + threadIdx.x] = make_float4(0.f, 0.f, 0.f, 0.f);
}

// ---- GEMM1: P[v][b] = dot(C[h][v][:], u[b][:]) ----
// 4 waves K-split (wave w owns k in [w*32,w*32+32)), lane = b.
// ALL hot state in named registers (u0..u7, c0..c7) — no local arrays,
// so nothing can be demoted to scratch. 64 rows/block in 4 groups of 16;
// cross-wave K-partials combined via 16 KB LDS pbuf.
__global__ __launch_bounds__(256, 3) void k_gemm_p(const float* __restrict__ Ch,
                                                   const float* __restrict__ u,
                                                   float* __restrict__ P) {
    __shared__ float uT[DD * 65];        // [d][b], stride 65 (33.3 KB)
    __shared__ float pbuf[4 * 16 * 64];  // [w][vi][b] partials (16 KB)
    const int t = threadIdx.x;
    const int lane = t & 63;  // = b
    const int w = __builtin_amdgcn_readfirstlane(t >> 6);
    const int ko = w * 32;

    // stage u ([b][d] global, coalesced float4) transposed into uT [d][b]
#pragma unroll
    for (int k = 0; k < 8; ++k) {
        const int f = (k * 256 + t) * 4;  // f = b*128 + d
        const int b = f >> 7, d = f & 127;
        const float4 val = *(const float4*)(u + f);
        uT[(d + 0) * 65 + b] = val.x;
        uT[(d + 1) * 65 + b] = val.y;
        uT[(d + 2) * 65 + b] = val.z;
        uT[(d + 3) * 65 + b] = val.w;
    }
    __syncthreads();

#define LD_U(i) make_float4(uT[(ko + 4 * i + 0) * 65 + lane], \
                            uT[(ko + 4 * i + 1) * 65 + lane], \
                            uT[(ko + 4 * i + 2) * 65 + lane], \
                            uT[(ko + 4 * i + 3) * 65 + lane])
    const float4 u0 = LD_U(0), u1 = LD_U(1), u2 = LD_U(2), u3 = LD_U(3);
    const float4 u4 = LD_U(4), u5 = LD_U(5), u6 = LD_U(6), u7 = LD_U(7);
#undef LD_U

    const int v00 = blockIdx.x * 64;
    for (int g = 0; g < 4; ++g) {
        const int vg0 = v00 + g * 16;
#pragma unroll
        for (int vi = 0; vi < 16; ++vi) {
            const int v = vg0 + vi;  // wave-uniform
            float a = 0.f;
            if (v < VV) {
                const float4* __restrict__ Cr =
                    (const float4*)(Ch + (size_t)v * DD + ko);
                const float4 c0 = Cr[0], c1 = Cr[1], c2 = Cr[2], c3 = Cr[3];
                const float4 c4 = Cr[4], c5 = Cr[5], c6 = Cr[6], c7 = Cr[7];
                const float s0 = dot4(c0, u0) + dot4(c1, u1);
                const float s1 = dot4(c2, u2) + dot4(c3, u3);
                const float s2 = dot4(c4, u4) + dot4(c5, u5);
                const float s3 = dot4(c6, u6) + dot4(c7, u7);
                a = (s0 + s1) + (s2 + s3);
            }
            pbuf[w * 1024 + vi * 64 + lane] = a;
        }
        __syncthreads();
#pragma unroll
        for (int k = 0; k < 4; ++k) {
            const int o = k * 256 + t;  // o = vi*64 + b
            const float sum =
                pbuf[o] + pbuf[1024 + o] + pbuf[2048 + o] + pbuf[3072 + o];
            const int v = vg0 + (o >> 6);
            if (v < VV) P[(size_t)v * 64 + (o & 63)] = sum;
        }
        __syncthreads();
    }
}

// ---- gather scores: s[m*64+b] = sum_t (tok!=0) P[tok*64+b] ----
__global__ __launch_bounds__(256) void k_gather(const int* __restrict__ st,
                                                const float* __restrict__ P,
                                                float* __restrict__ s) {
    const int g = blockIdx.x * 256 + threadIdx.x;  // g = m*64+b
    const int b = g & 63;
    const int4 tk = *(const int4*)(st + (size_t)g * 4);
    float acc = 0.f;
    if (tk.x) acc += P[(size_t)tk.x * 64 + b];
    if (tk.y) acc += P[(size_t)tk.y * 64 + b];
    if (tk.z) acc += P[(size_t)tk.z * 64 + b];
    if (tk.w) acc += P[(size_t)tk.w * 64 + b];
    s[g] = acc;
}

// ---- softmax over m for each b; s layout [m][b] ----
__global__ __launch_bounds__(256) void k_softmax(float* __restrict__ s) {
    const int b = blockIdx.x;
    const int tid = threadIdx.x;  // 256
    __shared__ float redmax[4];
    __shared__ float redsum[4];

    float v0 = s[(size_t)(tid + 0) * 64 + b];
    float v1 = s[(size_t)(tid + 256) * 64 + b];
    float v2 = s[(size_t)(tid + 512) * 64 + b];
    float v3 = s[(size_t)(tid + 768) * 64 + b];
    float v4 = s[(size_t)(tid + 1024) * 64 + b];
    float v5 = s[(size_t)(tid + 1280) * 64 + b];
    float v6 = s[(size_t)(tid + 1536) * 64 + b];
    float v7 = s[(size_t)(tid + 1792) * 64 + b];

    float mx = fmaxf(fmaxf(fmaxf(v0, v1), fmaxf(v2, v3)),
                     fmaxf(fmaxf(v4, v5), fmaxf(v6, v7)));
#pragma unroll
    for (int off = 32; off; off >>= 1) mx = fmaxf(mx, __shfl_xor(mx, off, 64));
    if ((tid & 63) == 0) redmax[tid >> 6] = mx;
    __syncthreads();
    const float gmax = fmaxf(fmaxf(redmax[0], redmax[1]),
                             fmaxf(redmax[2], redmax[3]));

    v0 = __expf(v0 - gmax); v1 = __expf(v1 - gmax);
    v2 = __expf(v2 - gmax); v3 = __expf(v3 - gmax);
    v4 = __expf(v4 - gmax); v5 = __expf(v5 - gmax);
    v6 = __expf(v6 - gmax); v7 = __expf(v7 - gmax);
    float sum = ((v0 + v1) + (v2 + v3)) + ((v4 + v5) + (v6 + v7));
#pragma unroll
    for (int off = 32; off; off >>= 1) sum += __shfl_xor(sum, off, 64);
    if ((tid & 63) == 0) redsum[tid >> 6] = sum;
    __syncthreads();
    const float inv = 1.f / (redsum[0] + redsum[1] + redsum[2] + redsum[3]);

    s[(size_t)(tid + 0) * 64 + b] = v0 * inv;
    s[(size_t)(tid + 256) * 64 + b] = v1 * inv;
    s[(size_t)(tid + 512) * 64 + b] = v2 * inv;
    s[(size_t)(tid + 768) * 64 + b] = v3 * inv;
    s[(size_t)(tid + 1024) * 64 + b] = v4 * inv;
    s[(size_t)(tid + 1280) * 64 + b] = v5 * inv;
    s[(size_t)(tid + 1536) * 64 + b] = v6 * inv;
    s[(size_t)(tid + 1792) * 64 + b] = v7 * inv;
}

// ---- scatter: W[tok*64+b] += prob[m,b] ----
__global__ __launch_bounds__(256) void k_scatter(const int* __restrict__ st,
                                                 const float* __restrict__ s,
                                                 float* __restrict__ W) {
    const int g = blockIdx.x * 256 + threadIdx.x;  // g = m*64+b
    const int b = g & 63;
    const float p = s[g];
    const int4 tk = *(const int4*)(st + (size_t)g * 4);
    if (tk.x) atomicAdd(W + (size_t)tk.x * 64 + b, p);
    if (tk.y) atomicAdd(W + (size_t)tk.y * 64 + b, p);
    if (tk.z) atomicAdd(W + (size_t)tk.z * 64 + b, p);
    if (tk.w) atomicAdd(W + (size_t)tk.w * 64 + b, p);
}

// ---- GEMM2 partials: upart[blk][b][d] = sum_{v in blk} W[v][b] * C2[v][d] ----
// d = t&127 (wave pair), b-half = t>>7 -> 32 named accumulators (a0..a7 f4).
// C2 coalesced, W row wave-uniform float4s. 64 v per block, NO atomics:
// partials written to upart, reduced by k_reduce_u.
__global__ __launch_bounds__(256, 4) void k_gemm_o(const float* __restrict__ C2,
                                                   const float* __restrict__ W,
                                                   float* __restrict__ upart) {
    const int t = threadIdx.x;
    const int d = t & 127;
    const int b0 = __builtin_amdgcn_readfirstlane(t >> 7) * 32;
    const int vbase = blockIdx.x * 64;

    float4 a0 = make_float4(0.f, 0.f, 0.f, 0.f), a1 = a0, a2 = a0, a3 = a0;
    float4 a4 = a0, a5 = a0, a6 = a0, a7 = a0;

#define ACC4(reg, wv)                                  \
    reg.x = __builtin_fmaf(wv.x, c, reg.x);            \
    reg.y = __builtin_fmaf(wv.y, c, reg.y);            \
    reg.z = __builtin_fmaf(wv.z, c, reg.z);            \
    reg.w = __builtin_fmaf(wv.w, c, reg.w);

#pragma unroll 2
    for (int i = 0; i < 64; ++i) {
        const int v = vbase + i;  // wave-uniform
        if (v < VV) {
            const float c = C2[(size_t)v * DD + d];
            const float4* __restrict__ Wr =
                (const float4*)(W + (size_t)v * 64 + b0);
            const float4 w0 = Wr[0], w1 = Wr[1], w2 = Wr[2], w3 = Wr[3];
            const float4 w4 = Wr[4], w5 = Wr[5], w6 = Wr[6], w7 = Wr[7];
            ACC4(a0, w0) ACC4(a1, w1) ACC4(a2, w2) ACC4(a3, w3)
            ACC4(a4, w4) ACC4(a5, w5) ACC4(a6, w6) ACC4(a7, w7)
        }
    }
#undef ACC4

    float* __restrict__ up = upart + (size_t)blockIdx.x * (BB * DD) + d;
#define ST4(k, reg)                          \
    up[(b0 + 4 * k + 0) * DD] = reg.x;       \
    up[(b0 + 4 * k + 1) * DD] = reg.y;       \
    up[(b0 + 4 * k + 2) * DD] = reg.z;       \
    up[(b0 + 4 * k + 3) * DD] = reg.w;
    ST4(0, a0) ST4(1, a1) ST4(2, a2) ST4(3, a3)
    ST4(4, a4) ST4(5, a5) ST4(6, a6) ST4(7, a7)
#undef ST4
}

// ---- reduce upart over NBLK_O blocks into u (8 k-chunks of 98) ----
__global__ __launch_bounds__(256) void k_reduce_u(const float* __restrict__ up,
                                                  float* __restrict__ u) {
    const int jc = blockIdx.x & 31;   // 32 j-chunks of 256
    const int kc = blockIdx.x >> 5;   // 8 k-chunks of 98
    const int j = jc * 256 + threadIdx.x;
    const float* __restrict__ p = up + (size_t)kc * 98 * (BB * DD) + j;
    float s = 0.f;
#pragma unroll 7
    for (int k = 0; k < 98; ++k) s += p[(size_t)k * (BB * DD)];
    atomicAdd(u + j, s);
}

// ---- copy u -> out ----
__global__ void k_copy(const float* __restrict__ u, float* __restrict__ out) {
    const int i = blockIdx.x * 256 + threadIdx.x;
    out[i] = u[i];
}

extern "C" void kernel_launch(void* const* d_in, const int* in_sizes, int n_in,
                              void* d_out, int out_size, void* d_ws, size_t ws_size,
                              hipStream_t stream) {
    const int* st = (const int*)d_in[0];
    const float* C = (const float*)d_in[1];

    float* u  = (float*)d_ws;            // 8192 f, layout [b][d]
    float* s  = u + BB * DD;             // 131072 f, layout [m][b]
    float* PW = s + MM * BB;             // VPAD*64 f = 12.85 MB (P/W share)
    float* up = PW + (size_t)VPAD * BB;  // 784*8192 f = 25.7 MB

    k_zero<<<(BB * DD) / 256, 256, 0, stream>>>(u);

    for (int hop = 0; hop < 3; ++hop) {
        const float* Ch  = C + (size_t)hop * VV * DD;
        const float* Ch1 = C + (size_t)(hop + 1) * VV * DD;

        k_gemm_p<<<VPAD / 64, 256, 0, stream>>>(Ch, u, PW);          // 784
        k_gather<<<(MM * BB) / 256, 256, 0, stream>>>(st, PW, s);    // 512
        k_softmax<<<BB, 256, 0, stream>>>(s);                        // 64
        k_zero_w<<<(VPAD * BB / 4) / 256, 256, 0, stream>>>((float4*)PW);
        k_scatter<<<(MM * BB) / 256, 256, 0, stream>>>(st, s, PW);   // 512
        k_gemm_o<<<NBLK_O, 256, 0, stream>>>(Ch1, PW, up);           // 784
        k_reduce_u<<<256, 256, 0, stream>>>(up, u);                  // 256
    }

    k_copy<<<(BB * DD) / 256, 256, 0, stream>>>(u, (float*)d_out);
}

// Round 7
// 409.635 us; speedup vs baseline: 1.4964x; 1.4964x over previous
//
#include <hip/hip_runtime.h>

#define MM 2048     // memory slots
#define BB 64       // batch
#define TT 4        // tokens per slot
#define DD 128      // embed dim
#define VV 50000    // vocab
#define VPAD 50176  // VV rounded up to multiple of 256

typedef float f4v __attribute__((ext_vector_type(4)));
typedef short s8v __attribute__((ext_vector_type(8)));

// float -> bf16 bits (RNE)
__device__ __forceinline__ unsigned short f2bf(float f) {
    unsigned int u = __float_as_uint(f);
    u = u + 0x7FFFu + ((u >> 16) & 1u);
    return (unsigned short)(u >> 16);
}

// ---- zero u ----
__global__ void k_zero(float* __restrict__ u) {
    u[blockIdx.x * 256 + threadIdx.x] = 0.f;
}

// ---- zero W ----
__global__ void k_zero_w(float4* __restrict__ w) {
    w[blockIdx.x * 256 + threadIdx.x] = make_float4(0.f, 0.f, 0.f, 0.f);
}

// ---- GEMM1 (MFMA bf16): P[v][b] = dot(C[h][v][:], u[b][:]) ----
// Block: 64 v-rows, all 64 b, K=128. LDS rows[128][136] bf16:
// rows 0..63 = C tile (A operand, [m][k]), rows 64..127 = u (BT, [n][k]).
// Wave w: v-rows 16w..16w+15; 4 k-steps x 4 b-tiles of 16x16x32 MFMA.
__global__ __launch_bounds__(256, 4) void k_gemm_p(const float* __restrict__ Ch,
                                                   const float* __restrict__ u,
                                                   float* __restrict__ P) {
    __shared__ short lds[128 * 136];  // 34.8 KB bf16
    const int t = threadIdx.x;
    const int v0 = blockIdx.x * 64;

    // stage: 128 rows x 128 floats -> bf16. coalesced float4 loads.
#pragma unroll
    for (int i = 0; i < 16; ++i) {
        const int G = i * 256 + t;        // f4-index
        const int row = G >> 5;           // 0..127
        const int c4 = G & 31;            // f4 within row
        float4 val;
        if (row < 64) {
            const int v = v0 + row;
            val = (v < VV) ? *(const float4*)(Ch + (size_t)v * DD + c4 * 4)
                           : make_float4(0.f, 0.f, 0.f, 0.f);
        } else {
            val = *(const float4*)(u + (size_t)(row - 64) * DD + c4 * 4);
        }
        const unsigned int lo = ((unsigned int)f2bf(val.y) << 16) | f2bf(val.x);
        const unsigned int hi = ((unsigned int)f2bf(val.w) << 16) | f2bf(val.z);
        *(uint2*)(lds + row * 136 + c4 * 4) = make_uint2(lo, hi);
    }
    __syncthreads();

    const int l = t & 63;
    const int w = t >> 6;       // wave id 0..3
    const int quad = l >> 4;    // 0..3
    const int n16 = l & 15;

    const int arow = (16 * w + n16) * 136;
    const int brow0 = (64 + 0 * 16 + n16) * 136;
    const int brow1 = (64 + 1 * 16 + n16) * 136;
    const int brow2 = (64 + 2 * 16 + n16) * 136;
    const int brow3 = (64 + 3 * 16 + n16) * 136;

    f4v ac0 = {0.f, 0.f, 0.f, 0.f}, ac1 = ac0, ac2 = ac0, ac3 = ac0;

#pragma unroll
    for (int s = 0; s < 4; ++s) {
        const int ko = s * 32 + quad * 8;
        const s8v av = *(const s8v*)(lds + arow + ko);
        const s8v b0 = *(const s8v*)(lds + brow0 + ko);
        const s8v b1 = *(const s8v*)(lds + brow1 + ko);
        const s8v b2 = *(const s8v*)(lds + brow2 + ko);
        const s8v b3 = *(const s8v*)(lds + brow3 + ko);
        ac0 = __builtin_amdgcn_mfma_f32_16x16x32_bf16(av, b0, ac0, 0, 0, 0);
        ac1 = __builtin_amdgcn_mfma_f32_16x16x32_bf16(av, b1, ac1, 0, 0, 0);
        ac2 = __builtin_amdgcn_mfma_f32_16x16x32_bf16(av, b2, ac2, 0, 0, 0);
        ac3 = __builtin_amdgcn_mfma_f32_16x16x32_bf16(av, b3, ac3, 0, 0, 0);
    }

    // D layout: n = lane&15, m = quad*4 + reg
    const int vbase = v0 + 16 * w + quad * 4;
#pragma unroll
    for (int r = 0; r < 4; ++r) {
        float* __restrict__ Pr = P + (size_t)(vbase + r) * 64 + n16;
        Pr[0]  = ac0[r];
        Pr[16] = ac1[r];
        Pr[32] = ac2[r];
        Pr[48] = ac3[r];
    }
}

// ---- gather scores: s[m*64+b] = sum_t (tok!=0) P[tok*64+b] ----
__global__ __launch_bounds__(256) void k_gather(const int* __restrict__ st,
                                                const float* __restrict__ P,
                                                float* __restrict__ s) {
    const int g = blockIdx.x * 256 + threadIdx.x;  // g = m*64+b
    const int b = g & 63;
    const int4 tk = *(const int4*)(st + (size_t)g * 4);
    float acc = 0.f;
    if (tk.x) acc += P[(size_t)tk.x * 64 + b];
    if (tk.y) acc += P[(size_t)tk.y * 64 + b];
    if (tk.z) acc += P[(size_t)tk.z * 64 + b];
    if (tk.w) acc += P[(size_t)tk.w * 64 + b];
    s[g] = acc;
}

// ---- softmax over m for each b; s layout [m][b] ----
__global__ __launch_bounds__(256) void k_softmax(float* __restrict__ s) {
    const int b = blockIdx.x;
    const int tid = threadIdx.x;  // 256
    __shared__ float redmax[4];
    __shared__ float redsum[4];

    float v0 = s[(size_t)(tid + 0) * 64 + b];
    float v1 = s[(size_t)(tid + 256) * 64 + b];
    float v2 = s[(size_t)(tid + 512) * 64 + b];
    float v3 = s[(size_t)(tid + 768) * 64 + b];
    float v4 = s[(size_t)(tid + 1024) * 64 + b];
    float v5 = s[(size_t)(tid + 1280) * 64 + b];
    float v6 = s[(size_t)(tid + 1536) * 64 + b];
    float v7 = s[(size_t)(tid + 1792) * 64 + b];

    float mx = fmaxf(fmaxf(fmaxf(v0, v1), fmaxf(v2, v3)),
                     fmaxf(fmaxf(v4, v5), fmaxf(v6, v7)));
#pragma unroll
    for (int off = 32; off; off >>= 1) mx = fmaxf(mx, __shfl_xor(mx, off, 64));
    if ((tid & 63) == 0) redmax[tid >> 6] = mx;
    __syncthreads();
    const float gmax = fmaxf(fmaxf(redmax[0], redmax[1]),
                             fmaxf(redmax[2], redmax[3]));

    v0 = __expf(v0 - gmax); v1 = __expf(v1 - gmax);
    v2 = __expf(v2 - gmax); v3 = __expf(v3 - gmax);
    v4 = __expf(v4 - gmax); v5 = __expf(v5 - gmax);
    v6 = __expf(v6 - gmax); v7 = __expf(v7 - gmax);
    float sum = ((v0 + v1) + (v2 + v3)) + ((v4 + v5) + (v6 + v7));
#pragma unroll
    for (int off = 32; off; off >>= 1) sum += __shfl_xor(sum, off, 64);
    if ((tid & 63) == 0) redsum[tid >> 6] = sum;
    __syncthreads();
    const float inv = 1.f / (redsum[0] + redsum[1] + redsum[2] + redsum[3]);

    s[(size_t)(tid + 0) * 64 + b] = v0 * inv;
    s[(size_t)(tid + 256) * 64 + b] = v1 * inv;
    s[(size_t)(tid + 512) * 64 + b] = v2 * inv;
    s[(size_t)(tid + 768) * 64 + b] = v3 * inv;
    s[(size_t)(tid + 1024) * 64 + b] = v4 * inv;
    s[(size_t)(tid + 1280) * 64 + b] = v5 * inv;
    s[(size_t)(tid + 1536) * 64 + b] = v6 * inv;
    s[(size_t)(tid + 1792) * 64 + b] = v7 * inv;
}

// ---- scatter: W[tok*64+b] += prob[m,b] ----
__global__ __launch_bounds__(256) void k_scatter(const int* __restrict__ st,
                                                 const float* __restrict__ s,
                                                 float* __restrict__ W) {
    const int g = blockIdx.x * 256 + threadIdx.x;  // g = m*64+b
    const int b = g & 63;
    const float p = s[g];
    const int4 tk = *(const int4*)(st + (size_t)g * 4);
    if (tk.x) atomicAdd(W + (size_t)tk.x * 64 + b, p);
    if (tk.y) atomicAdd(W + (size_t)tk.y * 64 + b, p);
    if (tk.z) atomicAdd(W + (size_t)tk.z * 64 + b, p);
    if (tk.w) atomicAdd(W + (size_t)tk.w * 64 + b, p);
}

// ---- GEMM2 (fp32 tiled): upart += W[v][b] * C2[v][d] over 128-v slice ----
// Block 256 thr, v-slice 128 (2 sub-chunks of 64 staged in LDS).
// Waves 0,1 = k-group 0 (kk 0..31), waves 2,3 = group 1 (kk 32..63).
// Thread tile 8b x 8d, all accumulators NAMED f4v. Partials to upart.
__global__ __launch_bounds__(256, 3) void k_gemm_o(const float* __restrict__ C2,
                                                   const float* __restrict__ W,
                                                   float* __restrict__ upart) {
    __shared__ float Wl[64 * 68];    // 17.4 KB
    __shared__ float Cl[64 * 136];   // 34.8 KB
    const int t = threadIdx.x;
    const int g = t >> 7;            // k-group
    const int b0 = ((t >> 4) & 7) * 8;
    const int d0 = (t & 15) * 8;
    const int vb = blockIdx.x * 128;

    f4v a0l = {0.f, 0.f, 0.f, 0.f}, a0h = a0l, a1l = a0l, a1h = a0l;
    f4v a2l = a0l, a2h = a0l, a3l = a0l, a3h = a0l;
    f4v a4l = a0l, a4h = a0l, a5l = a0l, a5h = a0l;
    f4v a6l = a0l, a6h = a0l, a7l = a0l, a7h = a0l;

    for (int cc = 0; cc < 2; ++cc) {
        const int vc = vb + cc * 64;
        // stage W chunk: 64 rows x 64 f
#pragma unroll
        for (int i = 0; i < 4; ++i) {
            const int G = i * 256 + t;
            const int row = G >> 4, c4 = G & 15;
            *(float4*)&Wl[row * 68 + c4 * 4] =
                *(const float4*)(W + (size_t)(vc + row) * 64 + c4 * 4);
        }
        // stage C2 chunk: 64 rows x 128 f (guard v < VV)
#pragma unroll
        for (int i = 0; i < 8; ++i) {
            const int G = i * 256 + t;
            const int row = G >> 5, c4 = G & 31;
            const int v = vc + row;
            float4 val = (v < VV) ? *(const float4*)(C2 + (size_t)v * DD + c4 * 4)
                                  : make_float4(0.f, 0.f, 0.f, 0.f);
            *(float4*)&Cl[row * 136 + c4 * 4] = val;
        }
        __syncthreads();

#define FMA_ROW(al, ah, wc)            \
    al += wc * cA; ah += wc * cB;

#pragma unroll
        for (int j = 0; j < 32; ++j) {
            const int kk = g * 32 + j;
            const f4v wA = *(const f4v*)&Wl[kk * 68 + b0];
            const f4v wB = *(const f4v*)&Wl[kk * 68 + b0 + 4];
            const f4v cA = *(const f4v*)&Cl[kk * 136 + d0];
            const f4v cB = *(const f4v*)&Cl[kk * 136 + d0 + 4];
            FMA_ROW(a0l, a0h, wA[0]) FMA_ROW(a1l, a1h, wA[1])
            FMA_ROW(a2l, a2h, wA[2]) FMA_ROW(a3l, a3h, wA[3])
            FMA_ROW(a4l, a4h, wB[0]) FMA_ROW(a5l, a5h, wB[1])
            FMA_ROW(a6l, a6h, wB[2]) FMA_ROW(a7l, a7h, wB[3])
        }
#undef FMA_ROW
        __syncthreads();
    }

    float* __restrict__ up =
        upart + (size_t)(blockIdx.x * 2 + g) * (BB * DD);
#define ST_ROW(i, al, ah)                              \
    *(f4v*)(up + (b0 + i) * DD + d0) = al;             \
    *(f4v*)(up + (b0 + i) * DD + d0 + 4) = ah;
    ST_ROW(0, a0l, a0h) ST_ROW(1, a1l, a1h) ST_ROW(2, a2l, a2h)
    ST_ROW(3, a3l, a3h) ST_ROW(4, a4l, a4h) ST_ROW(5, a5l, a5h)
    ST_ROW(6, a6l, a6h) ST_ROW(7, a7l, a7h)
#undef ST_ROW
}

// ---- reduce upart over 784 slots into u ----
__global__ __launch_bounds__(256) void k_reduce_u(const float* __restrict__ up,
                                                  float* __restrict__ u) {
    const int jc = blockIdx.x & 31;   // 32 j-chunks of 256
    const int kc = blockIdx.x >> 5;   // 8 k-chunks of 98
    const int j = jc * 256 + threadIdx.x;
    const float* __restrict__ p = up + (size_t)kc * 98 * (BB * DD) + j;
    float s = 0.f;
#pragma unroll 7
    for (int k = 0; k < 98; ++k) s += p[(size_t)k * (BB * DD)];
    atomicAdd(u + j, s);
}

// ---- copy u -> out ----
__global__ void k_copy(const float* __restrict__ u, float* __restrict__ out) {
    const int i = blockIdx.x * 256 + threadIdx.x;
    out[i] = u[i];
}

extern "C" void kernel_launch(void* const* d_in, const int* in_sizes, int n_in,
                              void* d_out, int out_size, void* d_ws, size_t ws_size,
                              hipStream_t stream) {
    const int* st = (const int*)d_in[0];
    const float* C = (const float*)d_in[1];

    float* u  = (float*)d_ws;            // 8192 f, layout [b][d]
    float* s  = u + BB * DD;             // 131072 f, layout [m][b]
    float* PW = s + MM * BB;             // VPAD*64 f = 12.85 MB (P/W share)
    float* up = PW + (size_t)VPAD * BB;  // 784*8192 f = 25.7 MB

    k_zero<<<(BB * DD) / 256, 256, 0, stream>>>(u);

    for (int hop = 0; hop < 3; ++hop) {
        const float* Ch  = C + (size_t)hop * VV * DD;
        const float* Ch1 = C + (size_t)(hop + 1) * VV * DD;

        k_gemm_p<<<VPAD / 64, 256, 0, stream>>>(Ch, u, PW);          // 784
        k_gather<<<(MM * BB) / 256, 256, 0, stream>>>(st, PW, s);    // 512
        k_softmax<<<BB, 256, 0, stream>>>(s);                        // 64
        k_zero_w<<<(VPAD * BB / 4) / 256, 256, 0, stream>>>((float4*)PW);
        k_scatter<<<(MM * BB) / 256, 256, 0, stream>>>(st, s, PW);   // 512
        k_gemm_o<<<VPAD / 128, 256, 0, stream>>>(Ch1, PW, up);       // 392
        k_reduce_u<<<256, 256, 0, stream>>>(up, u);                  // 256
    }

    k_copy<<<(BB * DD) / 256, 256, 0, stream>>>(u, (float*)d_out);
}